// Round 3
// baseline (984.460 us; speedup 1.0000x reference)
//
#include <hip/hip_runtime.h>
#include <hip/hip_bf16.h>
#include <cstdint>
#include <cstddef>

#define N_NODES 262143
#define LEAF0   131071
#define N_LEAF  131072
#define HSZ     256
#define XSZ     300
#define KX      320        // XSZ padded to multiple of 32
#define KU      512
#define GATES   1024       // 4*H
#define WCOLS   512        // 2*H
#define BM      128
#define BK      32
#define TD      6          // tail kernel handles d = TD..0

typedef short bf16x8 __attribute__((ext_vector_type(8)));
typedef float f32x4 __attribute__((ext_vector_type(4)));

__device__ __forceinline__ unsigned short f2bf(float f) {
  union { float f; unsigned u; } v; v.f = f;
  unsigned r = v.u + 0x7FFFu + ((v.u >> 16) & 1u);   // RNE
  return (unsigned short)(r >> 16);
}
__device__ __forceinline__ unsigned cvt_pk(float lo, float hi) {
  unsigned r;
  asm("v_cvt_pk_bf16_f32 %0, %1, %2" : "=v"(r) : "v"(lo), "v"(hi));
  return r;
}
__device__ __forceinline__ bf16x8 pack8(f32x4 a0, f32x4 a1) {
  union { unsigned u[4]; bf16x8 v; } r;
  r.u[0] = cvt_pk(a0[0], a0[1]);
  r.u[1] = cvt_pk(a0[2], a0[3]);
  r.u[2] = cvt_pk(a1[0], a1[1]);
  r.u[3] = cvt_pk(a1[2], a1[3]);
  return r.v;
}
__device__ __forceinline__ void gld_lds16(const void* g, void* l) {
  __builtin_amdgcn_global_load_lds(
      (const __attribute__((address_space(1))) unsigned*)g,
      (__attribute__((address_space(3))) unsigned*)l, 16, 0, 0);
}
__device__ __forceinline__ float frcp(float x) { return __builtin_amdgcn_rcpf(x); }
__device__ __forceinline__ float fsig(float x) { return frcp(1.f + __expf(-x)); }
__device__ __forceinline__ float ftanh_(float x) { return 1.f - 2.f * frcp(1.f + __expf(2.f * x)); }

// ---------------------------------------------------------------------------
// Prep: cast + column-permute + transpose W and U into ws (bf16).
// U perm col p = 64*b + 16*g + j  <-  orig col 256*g + 16*b + j
// W perm col p = 32*b + 16*s + j  <-  orig col 256*s + 16*b + j
// ---------------------------------------------------------------------------
__global__ void k_prep(const float* __restrict__ W, const float* __restrict__ U,
                       unsigned short* __restrict__ Wt, unsigned short* __restrict__ Ut) {
  int tid = blockIdx.x * blockDim.x + threadIdx.x;
  const int totalU = GATES * KU;
  if (tid < totalU) {
    int p = tid >> 9;
    int k = tid & 511;
    int g = (p >> 4) & 3, b = p >> 6, j = p & 15;
    int oc = g * 256 + b * 16 + j;
    Ut[tid] = f2bf(U[(size_t)k * GATES + oc]);
  } else {
    int t2 = tid - totalU;
    if (t2 < WCOLS * KX) {
      int p = t2 / KX;
      int k = t2 - p * KX;
      int s = (p >> 4) & 1, b = p >> 5, j = p & 15;
      int oc = s * 256 + b * 16 + j;
      Wt[t2] = (k < XSZ) ? f2bf(W[(size_t)k * WCOLS + oc]) : (unsigned short)0;
    }
  }
}

// ---------------------------------------------------------------------------
// Leaf init: t = tanh(x @ W + bW); h -> hout(f32) [+hb bf16], c -> cbuf(f32)
// A = x f32 (swizzled 128B rows, cvt at read), B = Wt bf16 (swizzled 64B rows)
// ---------------------------------------------------------------------------
template<bool HB>
__global__ __launch_bounds__(256) void k_init_t(
    const float* __restrict__ x, const unsigned short* __restrict__ Wt,
    const float* __restrict__ bW, float* __restrict__ hout,
    unsigned short* __restrict__ hb, float* __restrict__ cbuf)
{
  __shared__ __attribute__((aligned(16))) float          As[BM * BK];   // 16 KB
  __shared__ __attribute__((aligned(16))) unsigned short Bs[BM * BK];   //  8 KB
  const int t = threadIdx.x;
  const int lane = t & 63, w = t >> 6;
  const int wm = w >> 1, wn = w & 1;
  const int lr = lane & 15, ls = lane >> 4;

  const int nwg = gridDim.x;
  const int wg = (blockIdx.x & 7) * (nwg >> 3) + (blockIdx.x >> 3);
  const int mblk = wg >> 2, nblk = wg & 3;
  const int tileM = mblk * BM, tileN = nblk * 128;

  f32x4 acc[4][4];
  #pragma unroll
  for (int i = 0; i < 4; ++i)
    #pragma unroll
    for (int j = 0; j < 4; ++j)
      #pragma unroll
      for (int e = 0; e < 4; ++e) acc[i][j][e] = 0.f;

  const int arow = lane >> 3;                  // 8 rows / 1KB issue (f32)
  const int aglog = (lane & 7) ^ arow;         // swizzled source granule
  const int brow = lane >> 2;                  // 16 rows / 1KB issue (bf16)
  const int bglog = (lane & 3) ^ (brow & 3);

  for (int k0 = 0; k0 < KX; k0 += BK) {
    #pragma unroll
    for (int s = 0; s < 4; ++s) {
      int e = w * 4 + s;
      int col = k0 + aglog * 4;
      if (col >= XSZ) col = 0;                 // pad lanes: finite garbage * B(0) = 0
      const float* g = x + (size_t)(LEAF0 + tileM + e * 8 + arow) * XSZ + col;
      gld_lds16(g, (char*)As + e * 1024);
    }
    #pragma unroll
    for (int s = 0; s < 2; ++s) {
      int e = w * 2 + s;
      const unsigned short* g = Wt + (size_t)(tileN + e * 16 + brow) * KX + k0 + bglog * 8;
      gld_lds16(g, (char*)Bs + e * 1024);
    }
    __syncthreads();
    bf16x8 af[4], bfv[4];
    #pragma unroll
    for (int i = 0; i < 4; ++i) {
      int row = wm * 64 + i * 16 + lr;
      int gx = (2 * ls) ^ (lr & 7);
      f32x4 a0 = *(const f32x4*)((const char*)As + row * 128 + (gx << 4));
      f32x4 a1 = *(const f32x4*)((const char*)As + row * 128 + ((gx ^ 1) << 4));
      af[i] = pack8(a0, a1);
    }
    #pragma unroll
    for (int j = 0; j < 4; ++j) {
      int row = wn * 64 + j * 16 + lr;
      bfv[j] = *(const bf16x8*)((const char*)Bs + row * 64 + ((ls ^ (lr & 3)) << 4));
    }
    #pragma unroll
    for (int i = 0; i < 4; ++i)
      #pragma unroll
      for (int j = 0; j < 4; ++j)
        acc[i][j] = __builtin_amdgcn_mfma_f32_16x16x32_bf16(af[i], bfv[j], acc[i][j], 0, 0, 0);
    __syncthreads();
  }

  const int pc = tileN + wn * 64;
  #pragma unroll
  for (int i = 0; i < 4; ++i) {
    #pragma unroll
    for (int tt = 0; tt < 2; ++tt) {
      int col = (pc >> 1) + tt * 16 + lr;
      #pragma unroll
      for (int rr = 0; rr < 4; ++rr) {
        int row = tileM + wm * 64 + i * 16 + ls * 4 + rr;
        float th = ftanh_(acc[i][2 * tt][rr]     + bW[col]);
        float tc = ftanh_(acc[i][2 * tt + 1][rr] + bW[256 + col]);
        size_t node = (size_t)LEAF0 + row;
        hout[node * HSZ + col] = th;
        cbuf[node * HSZ + col] = tc;
        if constexpr (HB) hb[node * HSZ + col] = f2bf(th);
      }
    }
  }
}

// ---------------------------------------------------------------------------
// One tree level, fused. HB: A staged straight from bf16 h-mirror (no cvt).
// ---------------------------------------------------------------------------
template<bool HB>
__global__ __launch_bounds__(256) void k_level_t(
    float* __restrict__ hbuf, unsigned short* __restrict__ hb,
    float* __restrict__ cbuf,
    const unsigned short* __restrict__ Ut, const float* __restrict__ bU,
    int a, int m)
{
  __shared__ __attribute__((aligned(16))) unsigned char  Asb[BM * BK * (HB ? 2 : 4)];
  __shared__ __attribute__((aligned(16))) unsigned short Bs[BM * BK];
  const int t = threadIdx.x;
  const int lane = t & 63, w = t >> 6;
  const int wm = w >> 1, wn = w & 1;
  const int lr = lane & 15, ls = lane >> 4;

  const int nwg = gridDim.x;
  const int wg = (blockIdx.x & 7) * (nwg >> 3) + (blockIdx.x >> 3);
  const int mblk = wg >> 3, nblk = wg & 7;
  const int tileM = mblk * BM, tileN = nblk * 128;

  f32x4 acc[4][4];
  #pragma unroll
  for (int i = 0; i < 4; ++i)
    #pragma unroll
    for (int j = 0; j < 4; ++j)
      #pragma unroll
      for (int e = 0; e < 4; ++e) acc[i][j][e] = 0.f;

  const unsigned short* AbaseH = hb   + (size_t)(2 * a + 1) * HSZ + (size_t)tileM * KU;
  const float*          AbaseF = hbuf + (size_t)(2 * a + 1) * HSZ + (size_t)tileM * KU;
  const unsigned short* Bbase  = Ut + (size_t)tileN * KU;

  const int arow = lane >> 3;
  const int aglog = (lane & 7) ^ arow;
  const int brow = lane >> 2;
  const int bglog = (lane & 3) ^ (brow & 3);

  for (int k0 = 0; k0 < KU; k0 += BK) {
    if constexpr (HB) {
      #pragma unroll
      for (int s = 0; s < 2; ++s) {
        int e = w * 2 + s;
        const unsigned short* g = AbaseH + (size_t)(e * 16 + brow) * KU + k0 + bglog * 8;
        gld_lds16(g, (char*)Asb + e * 1024);
      }
    } else {
      #pragma unroll
      for (int s = 0; s < 4; ++s) {
        int e = w * 4 + s;
        const float* g = AbaseF + (size_t)(e * 8 + arow) * KU + k0 + aglog * 4;
        gld_lds16(g, (char*)Asb + e * 1024);
      }
    }
    #pragma unroll
    for (int s = 0; s < 2; ++s) {
      int e = w * 2 + s;
      const unsigned short* g = Bbase + (size_t)(e * 16 + brow) * KU + k0 + bglog * 8;
      gld_lds16(g, (char*)Bs + e * 1024);
    }
    __syncthreads();
    bf16x8 af[4], bfv[4];
    #pragma unroll
    for (int i = 0; i < 4; ++i) {
      int row = wm * 64 + i * 16 + lr;
      if constexpr (HB) {
        af[i] = *(const bf16x8*)((const char*)Asb + row * 64 + ((ls ^ (lr & 3)) << 4));
      } else {
        int gx = (2 * ls) ^ (lr & 7);
        f32x4 a0 = *(const f32x4*)((const char*)Asb + row * 128 + (gx << 4));
        f32x4 a1 = *(const f32x4*)((const char*)Asb + row * 128 + ((gx ^ 1) << 4));
        af[i] = pack8(a0, a1);
      }
    }
    #pragma unroll
    for (int j = 0; j < 4; ++j) {
      int row = wn * 64 + j * 16 + lr;
      bfv[j] = *(const bf16x8*)((const char*)Bs + row * 64 + ((ls ^ (lr & 3)) << 4));
    }
    #pragma unroll
    for (int i = 0; i < 4; ++i)
      #pragma unroll
      for (int j = 0; j < 4; ++j)
        acc[i][j] = __builtin_amdgcn_mfma_f32_16x16x32_bf16(af[i], bfv[j], acc[i][j], 0, 0, 0);
    __syncthreads();
  }

  const int pc = tileN + wn * 64;            // frag j == gate g
  const int col = (pc >> 2) + lr;
  const float bi = bU[col], bo = bU[256 + col], bu = bU[512 + col], bff = bU[768 + col];
  #pragma unroll
  for (int i = 0; i < 4; ++i) {
    #pragma unroll
    for (int rr = 0; rr < 4; ++rr) {
      int noderow = tileM + wm * 64 + i * 16 + ls * 4 + rr;
      if (noderow < m) {
        float iv = fsig  (acc[i][0][rr] + bi);
        float ov = fsig  (acc[i][1][rr] + bo);
        float uv = ftanh_(acc[i][2][rr] + bu);
        float fv = fsig  (acc[i][3][rr] + bff);
        size_t node = (size_t)a + noderow;
        float cl = cbuf[(2 * node + 1) * HSZ + col];
        float cr = cbuf[(2 * node + 2) * HSZ + col];
        float cn = iv * uv + fv * (cl + cr);
        float hn = ov * ftanh_(cn);
        hbuf[node * HSZ + col] = hn;
        cbuf[node * HSZ + col] = cn;
        if constexpr (HB) hb[node * HSZ + col] = f2bf(hn);
      }
    }
  }
}

// ---------------------------------------------------------------------------
// Tail: levels d=TD..0 in ONE block (1024 thr = 16 waves). Wave w owns output
// cols [16w,16w+16). A/B read straight from global (L1/L2-hot, tiny).
// ---------------------------------------------------------------------------
template<bool HB>
__global__ __launch_bounds__(1024) void k_tail_t(
    float* __restrict__ hbuf, unsigned short* __restrict__ hb,
    float* __restrict__ cbuf,
    const unsigned short* __restrict__ Ut, const float* __restrict__ bU)
{
  const int t = threadIdx.x;
  const int lane = t & 63, w = t >> 6;
  const int lr = lane & 15, ls = lane >> 4;
  const int col = w * 16 + lr;
  const float bi = bU[col], bo = bU[256 + col], bu = bU[512 + col], bff = bU[768 + col];

  for (int d = TD; d >= 0; --d) {
    const int m = 1 << d, a = m - 1;
    const int mf = (m + 15) >> 4;
    f32x4 acc[4][4];
    #pragma unroll
    for (int i = 0; i < 4; ++i)
      #pragma unroll
      for (int g = 0; g < 4; ++g)
        #pragma unroll
        for (int e = 0; e < 4; ++e) acc[i][g][e] = 0.f;

    const size_t slab = (size_t)(2 * a + 1) * HSZ;
    for (int k0 = 0; k0 < KU; k0 += 32) {
      bf16x8 bv[4];
      #pragma unroll
      for (int g = 0; g < 4; ++g)
        bv[g] = *(const bf16x8*)(Ut + (size_t)(w * 64 + g * 16 + lr) * KU + k0 + ls * 8);
      #pragma unroll
      for (int i = 0; i < 4; ++i) {
        if (i < mf) {
          bf16x8 av;
          if constexpr (HB) {
            av = *(const bf16x8*)(hb + slab + (size_t)(i * 16 + lr) * KU + k0 + ls * 8);
          } else {
            f32x4 a0 = *(const f32x4*)(hbuf + slab + (size_t)(i * 16 + lr) * KU + k0 + ls * 8);
            f32x4 a1 = *(const f32x4*)(hbuf + slab + (size_t)(i * 16 + lr) * KU + k0 + ls * 8 + 4);
            av = pack8(a0, a1);
          }
          #pragma unroll
          for (int g = 0; g < 4; ++g)
            acc[i][g] = __builtin_amdgcn_mfma_f32_16x16x32_bf16(av, bv[g], acc[i][g], 0, 0, 0);
        }
      }
    }
    #pragma unroll
    for (int i = 0; i < 4; ++i) {
      if (i < mf) {
        #pragma unroll
        for (int rr = 0; rr < 4; ++rr) {
          int row = i * 16 + ls * 4 + rr;
          if (row < m) {
            float iv = fsig  (acc[i][0][rr] + bi);
            float ov = fsig  (acc[i][1][rr] + bo);
            float uv = ftanh_(acc[i][2][rr] + bu);
            float fv = fsig  (acc[i][3][rr] + bff);
            size_t node = (size_t)a + row;
            float cl = cbuf[(2 * node + 1) * HSZ + col];
            float cr = cbuf[(2 * node + 2) * HSZ + col];
            float cn = iv * uv + fv * (cl + cr);
            float hn = ov * ftanh_(cn);
            hbuf[node * HSZ + col] = hn;
            cbuf[node * HSZ + col] = cn;
            if constexpr (HB) hb[node * HSZ + col] = f2bf(hn);
          }
        }
      }
    }
    __syncthreads();   // next level reads this level's h/c (same CU, L1-coherent)
  }
}

// ---------------------------------------------------------------------------
extern "C" void kernel_launch(void* const* d_in, const int* in_sizes, int n_in,
                              void* d_out, int out_size, void* d_ws, size_t ws_size,
                              hipStream_t stream) {
  const float* x  = (const float*)d_in[0];
  const float* W  = (const float*)d_in[1];
  const float* bW = (const float*)d_in[2];
  const float* U  = (const float*)d_in[3];
  const float* bU = (const float*)d_in[4];
  // d_in[5] = children (int32) — structurally 2i+1/2i+2 (complete binary tree).
  float* hout = (float*)d_out;
  char*  ws   = (char*)d_ws;

  unsigned short* Ut = (unsigned short*)ws;                       // 1 MiB
  unsigned short* Wt = (unsigned short*)(ws + 1048576);           // 320 KiB
  float* cbuf = (float*)(ws + 1048576 + 327680);                  // 268.4 MB
  size_t base = 1048576 + 327680 + (size_t)N_NODES * HSZ * 4;
  size_t hbsz = (size_t)N_NODES * HSZ * 2;                        // 134.2 MB
  bool use_hb = (ws_size >= base + hbsz);
  unsigned short* hb = (unsigned short*)(ws + base);

  const int preptot = GATES * KU + WCOLS * KX;
  hipLaunchKernelGGL(k_prep, dim3((preptot + 255) / 256), dim3(256), 0, stream, W, U, Wt, Ut);

  if (use_hb) {
    hipLaunchKernelGGL(k_init_t<true>, dim3((N_LEAF / BM) * 4), dim3(256), 0, stream,
                       x, Wt, bW, hout, hb, cbuf);
    for (int d = 16; d > TD; --d) {
      int m = 1 << d, a = m - 1;
      hipLaunchKernelGGL(k_level_t<true>, dim3((m / BM) * 8), dim3(256), 0, stream,
                         hout, hb, cbuf, Ut, bU, a, m);
    }
    hipLaunchKernelGGL(k_tail_t<true>, dim3(1), dim3(1024), 0, stream,
                       hout, hb, cbuf, Ut, bU);
  } else {
    hipLaunchKernelGGL(k_init_t<false>, dim3((N_LEAF / BM) * 4), dim3(256), 0, stream,
                       x, Wt, bW, hout, hb, cbuf);
    for (int d = 16; d > TD; --d) {
      int m = 1 << d, a = m - 1;
      hipLaunchKernelGGL(k_level_t<false>, dim3((m / BM) * 8), dim3(256), 0, stream,
                         hout, hb, cbuf, Ut, bU, a, m);
    }
    hipLaunchKernelGGL(k_tail_t<false>, dim3(1), dim3(1024), 0, stream,
                       hout, hb, cbuf, Ut, bU);
  }
}

// Round 4
// 719.000 us; speedup vs baseline: 1.3692x; 1.3692x over previous
//
#include <hip/hip_runtime.h>
#include <hip/hip_bf16.h>
#include <cstdint>
#include <cstddef>

#define N_NODES 262143
#define LEAF0   131071
#define N_LEAF  131072
#define HSZ     256
#define XSZ     300
#define KX      320        // XSZ padded to multiple of 32
#define KU      512
#define GATES   1024       // 4*H
#define WCOLS   512        // 2*H
#define BM      128
#define BK      32

typedef short bf16x8 __attribute__((ext_vector_type(8)));
typedef float f32x4 __attribute__((ext_vector_type(4)));

__device__ __forceinline__ unsigned short f2bf(float f) {
  union { float f; unsigned u; } v; v.f = f;
  unsigned r = v.u + 0x7FFFu + ((v.u >> 16) & 1u);   // RNE
  return (unsigned short)(r >> 16);
}
__device__ __forceinline__ unsigned cvt_pk(float lo, float hi) {
  unsigned r;
  asm("v_cvt_pk_bf16_f32 %0, %1, %2" : "=v"(r) : "v"(lo), "v"(hi));
  return r;
}
__device__ __forceinline__ bf16x8 pack8(f32x4 a0, f32x4 a1) {
  union { unsigned u[4]; bf16x8 v; } r;
  r.u[0] = cvt_pk(a0[0], a0[1]);
  r.u[1] = cvt_pk(a0[2], a0[3]);
  r.u[2] = cvt_pk(a1[0], a1[1]);
  r.u[3] = cvt_pk(a1[2], a1[3]);
  return r.v;
}
__device__ __forceinline__ void gld_lds16(const void* g, void* l) {
  __builtin_amdgcn_global_load_lds(
      (const __attribute__((address_space(1))) unsigned*)g,
      (__attribute__((address_space(3))) unsigned*)l, 16, 0, 0);
}
__device__ __forceinline__ float frcp(float x) { return __builtin_amdgcn_rcpf(x); }
__device__ __forceinline__ float fsig(float x) { return frcp(1.f + __expf(-x)); }
__device__ __forceinline__ float ftanh_(float x) { return 1.f - 2.f * frcp(1.f + __expf(2.f * x)); }

// ---------------------------------------------------------------------------
// Prep: cast + column-permute + transpose W and U into ws (bf16).
// U perm col p = 64*b + 16*g + j  <-  orig col 256*g + 16*b + j
// W perm col p = 32*b + 16*s + j  <-  orig col 256*s + 16*b + j
// ---------------------------------------------------------------------------
__global__ void k_prep(const float* __restrict__ W, const float* __restrict__ U,
                       unsigned short* __restrict__ Wt, unsigned short* __restrict__ Ut) {
  int tid = blockIdx.x * blockDim.x + threadIdx.x;
  const int totalU = GATES * KU;
  if (tid < totalU) {
    int p = tid >> 9;
    int k = tid & 511;
    int g = (p >> 4) & 3, b = p >> 6, j = p & 15;
    int oc = g * 256 + b * 16 + j;
    Ut[tid] = f2bf(U[(size_t)k * GATES + oc]);
  } else {
    int t2 = tid - totalU;
    if (t2 < WCOLS * KX) {
      int p = t2 / KX;
      int k = t2 - p * KX;
      int s = (p >> 4) & 1, b = p >> 5, j = p & 15;
      int oc = s * 256 + b * 16 + j;
      Wt[t2] = (k < XSZ) ? f2bf(W[(size_t)k * WCOLS + oc]) : (unsigned short)0;
    }
  }
}

// ---------------------------------------------------------------------------
// Leaf init: t = tanh(x @ W + bW); h -> hout(f32) [+hb bf16], c -> cbuf(f32)
// A = x f32 (swizzled 128B rows, cvt at read), B = Wt bf16 (swizzled 64B rows)
// ---------------------------------------------------------------------------
template<bool HB>
__global__ __launch_bounds__(256) void k_init_t(
    const float* __restrict__ x, const unsigned short* __restrict__ Wt,
    const float* __restrict__ bW, float* __restrict__ hout,
    unsigned short* __restrict__ hb, float* __restrict__ cbuf)
{
  __shared__ __attribute__((aligned(16))) float          As[BM * BK];   // 16 KB
  __shared__ __attribute__((aligned(16))) unsigned short Bs[BM * BK];   //  8 KB
  const int t = threadIdx.x;
  const int lane = t & 63, w = t >> 6;
  const int wm = w >> 1, wn = w & 1;
  const int lr = lane & 15, ls = lane >> 4;

  const int nwg = gridDim.x;
  const int wg = (blockIdx.x & 7) * (nwg >> 3) + (blockIdx.x >> 3);
  const int mblk = wg >> 2, nblk = wg & 3;
  const int tileM = mblk * BM, tileN = nblk * 128;

  f32x4 acc[4][4];
  #pragma unroll
  for (int i = 0; i < 4; ++i)
    #pragma unroll
    for (int j = 0; j < 4; ++j)
      #pragma unroll
      for (int e = 0; e < 4; ++e) acc[i][j][e] = 0.f;

  const int arow = lane >> 3;                  // 8 rows / 1KB issue (f32)
  const int aglog = (lane & 7) ^ arow;         // swizzled source granule
  const int brow = lane >> 2;                  // 16 rows / 1KB issue (bf16)
  const int bglog = (lane & 3) ^ (brow & 3);

  for (int k0 = 0; k0 < KX; k0 += BK) {
    #pragma unroll
    for (int s = 0; s < 4; ++s) {
      int e = w * 4 + s;
      int col = k0 + aglog * 4;
      if (col >= XSZ) col = 0;                 // pad lanes: finite garbage * B(0) = 0
      const float* g = x + (size_t)(LEAF0 + tileM + e * 8 + arow) * XSZ + col;
      gld_lds16(g, (char*)As + e * 1024);
    }
    #pragma unroll
    for (int s = 0; s < 2; ++s) {
      int e = w * 2 + s;
      const unsigned short* g = Wt + (size_t)(tileN + e * 16 + brow) * KX + k0 + bglog * 8;
      gld_lds16(g, (char*)Bs + e * 1024);
    }
    __syncthreads();
    bf16x8 af[4], bfv[4];
    #pragma unroll
    for (int i = 0; i < 4; ++i) {
      int row = wm * 64 + i * 16 + lr;
      int gx = (2 * ls) ^ (lr & 7);
      f32x4 a0 = *(const f32x4*)((const char*)As + row * 128 + (gx << 4));
      f32x4 a1 = *(const f32x4*)((const char*)As + row * 128 + ((gx ^ 1) << 4));
      af[i] = pack8(a0, a1);
    }
    #pragma unroll
    for (int j = 0; j < 4; ++j) {
      int row = wn * 64 + j * 16 + lr;
      bfv[j] = *(const bf16x8*)((const char*)Bs + row * 64 + ((ls ^ (lr & 3)) << 4));
    }
    #pragma unroll
    for (int i = 0; i < 4; ++i)
      #pragma unroll
      for (int j = 0; j < 4; ++j)
        acc[i][j] = __builtin_amdgcn_mfma_f32_16x16x32_bf16(af[i], bfv[j], acc[i][j], 0, 0, 0);
    __syncthreads();
  }

  const int pc = tileN + wn * 64;
  #pragma unroll
  for (int i = 0; i < 4; ++i) {
    #pragma unroll
    for (int tt = 0; tt < 2; ++tt) {
      int col = (pc >> 1) + tt * 16 + lr;
      #pragma unroll
      for (int rr = 0; rr < 4; ++rr) {
        int row = tileM + wm * 64 + i * 16 + ls * 4 + rr;
        float th = ftanh_(acc[i][2 * tt][rr]     + bW[col]);
        float tc = ftanh_(acc[i][2 * tt + 1][rr] + bW[256 + col]);
        size_t node = (size_t)LEAF0 + row;
        hout[node * HSZ + col] = th;
        cbuf[node * HSZ + col] = tc;
        if constexpr (HB) hb[node * HSZ + col] = f2bf(th);
      }
    }
  }
}

// ---------------------------------------------------------------------------
// One tree level, fused. HB: A staged straight from bf16 h-mirror (no cvt).
// ---------------------------------------------------------------------------
template<bool HB>
__global__ __launch_bounds__(256) void k_level_t(
    float* __restrict__ hbuf, unsigned short* __restrict__ hb,
    float* __restrict__ cbuf,
    const unsigned short* __restrict__ Ut, const float* __restrict__ bU,
    int a, int m)
{
  __shared__ __attribute__((aligned(16))) unsigned char  Asb[BM * BK * (HB ? 2 : 4)];
  __shared__ __attribute__((aligned(16))) unsigned short Bs[BM * BK];
  const int t = threadIdx.x;
  const int lane = t & 63, w = t >> 6;
  const int wm = w >> 1, wn = w & 1;
  const int lr = lane & 15, ls = lane >> 4;

  const int nwg = gridDim.x;
  const int wg = (blockIdx.x & 7) * (nwg >> 3) + (blockIdx.x >> 3);
  const int mblk = wg >> 3, nblk = wg & 7;
  const int tileM = mblk * BM, tileN = nblk * 128;

  f32x4 acc[4][4];
  #pragma unroll
  for (int i = 0; i < 4; ++i)
    #pragma unroll
    for (int j = 0; j < 4; ++j)
      #pragma unroll
      for (int e = 0; e < 4; ++e) acc[i][j][e] = 0.f;

  const unsigned short* AbaseH = hb   + (size_t)(2 * a + 1) * HSZ + (size_t)tileM * KU;
  const float*          AbaseF = hbuf + (size_t)(2 * a + 1) * HSZ + (size_t)tileM * KU;
  const unsigned short* Bbase  = Ut + (size_t)tileN * KU;

  const int arow = lane >> 3;
  const int aglog = (lane & 7) ^ arow;
  const int brow = lane >> 2;
  const int bglog = (lane & 3) ^ (brow & 3);

  for (int k0 = 0; k0 < KU; k0 += BK) {
    if constexpr (HB) {
      #pragma unroll
      for (int s = 0; s < 2; ++s) {
        int e = w * 2 + s;
        const unsigned short* g = AbaseH + (size_t)(e * 16 + brow) * KU + k0 + bglog * 8;
        gld_lds16(g, (char*)Asb + e * 1024);
      }
    } else {
      #pragma unroll
      for (int s = 0; s < 4; ++s) {
        int e = w * 4 + s;
        const float* g = AbaseF + (size_t)(e * 8 + arow) * KU + k0 + aglog * 4;
        gld_lds16(g, (char*)Asb + e * 1024);
      }
    }
    #pragma unroll
    for (int s = 0; s < 2; ++s) {
      int e = w * 2 + s;
      const unsigned short* g = Bbase + (size_t)(e * 16 + brow) * KU + k0 + bglog * 8;
      gld_lds16(g, (char*)Bs + e * 1024);
    }
    __syncthreads();
    bf16x8 af[4], bfv[4];
    #pragma unroll
    for (int i = 0; i < 4; ++i) {
      int row = wm * 64 + i * 16 + lr;
      if constexpr (HB) {
        af[i] = *(const bf16x8*)((const char*)Asb + row * 64 + ((ls ^ (lr & 3)) << 4));
      } else {
        int gx = (2 * ls) ^ (lr & 7);
        f32x4 a0 = *(const f32x4*)((const char*)Asb + row * 128 + (gx << 4));
        f32x4 a1 = *(const f32x4*)((const char*)Asb + row * 128 + ((gx ^ 1) << 4));
        af[i] = pack8(a0, a1);
      }
    }
    #pragma unroll
    for (int j = 0; j < 4; ++j) {
      int row = wn * 64 + j * 16 + lr;
      bfv[j] = *(const bf16x8*)((const char*)Bs + row * 64 + ((ls ^ (lr & 3)) << 4));
    }
    #pragma unroll
    for (int i = 0; i < 4; ++i)
      #pragma unroll
      for (int j = 0; j < 4; ++j)
        acc[i][j] = __builtin_amdgcn_mfma_f32_16x16x32_bf16(af[i], bfv[j], acc[i][j], 0, 0, 0);
    __syncthreads();
  }

  const int pc = tileN + wn * 64;            // frag j == gate g
  const int col = (pc >> 2) + lr;
  const float bi = bU[col], bo = bU[256 + col], bu = bU[512 + col], bff = bU[768 + col];
  #pragma unroll
  for (int i = 0; i < 4; ++i) {
    #pragma unroll
    for (int rr = 0; rr < 4; ++rr) {
      int noderow = tileM + wm * 64 + i * 16 + ls * 4 + rr;
      if (noderow < m) {
        float iv = fsig  (acc[i][0][rr] + bi);
        float ov = fsig  (acc[i][1][rr] + bo);
        float uv = ftanh_(acc[i][2][rr] + bu);
        float fv = fsig  (acc[i][3][rr] + bff);
        size_t node = (size_t)a + noderow;
        float cl = cbuf[(2 * node + 1) * HSZ + col];
        float cr = cbuf[(2 * node + 2) * HSZ + col];
        float cn = iv * uv + fv * (cl + cr);
        float hn = ov * ftanh_(cn);
        hbuf[node * HSZ + col] = hn;
        cbuf[node * HSZ + col] = cn;
        if constexpr (HB) hb[node * HSZ + col] = f2bf(hn);
      }
    }
  }
}

// ---------------------------------------------------------------------------
extern "C" void kernel_launch(void* const* d_in, const int* in_sizes, int n_in,
                              void* d_out, int out_size, void* d_ws, size_t ws_size,
                              hipStream_t stream) {
  const float* x  = (const float*)d_in[0];
  const float* W  = (const float*)d_in[1];
  const float* bW = (const float*)d_in[2];
  const float* U  = (const float*)d_in[3];
  const float* bU = (const float*)d_in[4];
  // d_in[5] = children (int32) — structurally 2i+1/2i+2 (complete binary tree).
  float* hout = (float*)d_out;
  char*  ws   = (char*)d_ws;

  unsigned short* Ut = (unsigned short*)ws;                       // 1 MiB
  unsigned short* Wt = (unsigned short*)(ws + 1048576);           // 320 KiB
  float* cbuf = (float*)(ws + 1048576 + 327680);                  // 268.4 MB
  size_t base = 1048576 + 327680 + (size_t)N_NODES * HSZ * 4;
  size_t hbsz = (size_t)N_NODES * HSZ * 2;                        // 134.2 MB
  bool use_hb = (ws_size >= base + hbsz);
  unsigned short* hb = (unsigned short*)(ws + base);

  const int preptot = GATES * KU + WCOLS * KX;
  hipLaunchKernelGGL(k_prep, dim3((preptot + 255) / 256), dim3(256), 0, stream, W, U, Wt, Ut);

  if (use_hb) {
    hipLaunchKernelGGL(k_init_t<true>, dim3((N_LEAF / BM) * 4), dim3(256), 0, stream,
                       x, Wt, bW, hout, hb, cbuf);
    for (int d = 16; d >= 0; --d) {
      int m = 1 << d, a = m - 1;
      int mb = (m + BM - 1) / BM;
      hipLaunchKernelGGL(k_level_t<true>, dim3(mb * 8), dim3(256), 0, stream,
                         hout, hb, cbuf, Ut, bU, a, m);
    }
  } else {
    hipLaunchKernelGGL(k_init_t<false>, dim3((N_LEAF / BM) * 4), dim3(256), 0, stream,
                       x, Wt, bW, hout, hb, cbuf);
    for (int d = 16; d >= 0; --d) {
      int m = 1 << d, a = m - 1;
      int mb = (m + BM - 1) / BM;
      hipLaunchKernelGGL(k_level_t<false>, dim3(mb * 8), dim3(256), 0, stream,
                         hout, hb, cbuf, Ut, bU, a, m);
    }
  }
}

// Round 5
// 697.001 us; speedup vs baseline: 1.4124x; 1.0316x over previous
//
#include <hip/hip_runtime.h>
#include <hip/hip_bf16.h>
#include <cstdint>
#include <cstddef>

#define N_NODES 262143
#define LEAF0   131071
#define N_LEAF  131072
#define HSZ     256
#define XSZ     300
#define KX      320        // XSZ padded to multiple of 32
#define KU      512
#define GATES   1024       // 4*H
#define WCOLS   512        // 2*H
#define BM      128
#define BK      32

typedef short bf16x8 __attribute__((ext_vector_type(8)));
typedef float f32x4 __attribute__((ext_vector_type(4)));

__device__ __forceinline__ unsigned short f2bf(float f) {
  union { float f; unsigned u; } v; v.f = f;
  unsigned r = v.u + 0x7FFFu + ((v.u >> 16) & 1u);   // RNE
  return (unsigned short)(r >> 16);
}
__device__ __forceinline__ unsigned cvt_pk(float lo, float hi) {
  unsigned r;
  asm("v_cvt_pk_bf16_f32 %0, %1, %2" : "=v"(r) : "v"(lo), "v"(hi));
  return r;
}
__device__ __forceinline__ bf16x8 pack8(f32x4 a0, f32x4 a1) {
  union { unsigned u[4]; bf16x8 v; } r;
  r.u[0] = cvt_pk(a0[0], a0[1]);
  r.u[1] = cvt_pk(a0[2], a0[3]);
  r.u[2] = cvt_pk(a1[0], a1[1]);
  r.u[3] = cvt_pk(a1[2], a1[3]);
  return r.v;
}
__device__ __forceinline__ void gld_lds16(const void* g, void* l) {
  __builtin_amdgcn_global_load_lds(
      (const __attribute__((address_space(1))) unsigned*)g,
      (__attribute__((address_space(3))) unsigned*)l, 16, 0, 0);
}
__device__ __forceinline__ float frcp(float x) { return __builtin_amdgcn_rcpf(x); }
__device__ __forceinline__ float fsig(float x) { return frcp(1.f + __expf(-x)); }
__device__ __forceinline__ float ftanh_(float x) { return 1.f - 2.f * frcp(1.f + __expf(2.f * x)); }

// ---------------------------------------------------------------------------
// Prep: cast + column-permute + transpose W and U into ws (bf16).
// U perm col p = 64*b + 16*g + j  <-  orig col 256*g + 16*b + j
// W perm col p = 32*b + 16*s + j  <-  orig col 256*s + 16*b + j
// ---------------------------------------------------------------------------
__global__ void k_prep(const float* __restrict__ W, const float* __restrict__ U,
                       unsigned short* __restrict__ Wt, unsigned short* __restrict__ Ut) {
  int tid = blockIdx.x * blockDim.x + threadIdx.x;
  const int totalU = GATES * KU;
  if (tid < totalU) {
    int p = tid >> 9;
    int k = tid & 511;
    int g = (p >> 4) & 3, b = p >> 6, j = p & 15;
    int oc = g * 256 + b * 16 + j;
    Ut[tid] = f2bf(U[(size_t)k * GATES + oc]);
  } else {
    int t2 = tid - totalU;
    if (t2 < WCOLS * KX) {
      int p = t2 / KX;
      int k = t2 - p * KX;
      int s = (p >> 4) & 1, b = p >> 5, j = p & 15;
      int oc = s * 256 + b * 16 + j;
      Wt[t2] = (k < XSZ) ? f2bf(W[(size_t)k * WCOLS + oc]) : (unsigned short)0;
    }
  }
}

// ---------------------------------------------------------------------------
// Leaf init: t = tanh(x @ W + bW); h -> hout(f32) [+hb bf16], c -> cbuf(f32)
// 2-phase double-buffered staging: barrier -> issue stage(t+1) -> compute(t).
// ---------------------------------------------------------------------------
template<bool HB>
__global__ __launch_bounds__(256) void k_init_t(
    const float* __restrict__ x, const unsigned short* __restrict__ Wt,
    const float* __restrict__ bW, float* __restrict__ hout,
    unsigned short* __restrict__ hb, float* __restrict__ cbuf)
{
  __shared__ __attribute__((aligned(16))) float          As[2][BM * BK];   // 2x16 KB
  __shared__ __attribute__((aligned(16))) unsigned short Bs[2][BM * BK];   // 2x 8 KB
  const int t = threadIdx.x;
  const int lane = t & 63, w = t >> 6;
  const int wm = w >> 1, wn = w & 1;
  const int lr = lane & 15, ls = lane >> 4;

  const int nwg = gridDim.x;
  const int wg = (blockIdx.x & 7) * (nwg >> 3) + (blockIdx.x >> 3);
  const int mblk = wg >> 2, nblk = wg & 3;
  const int tileM = mblk * BM, tileN = nblk * 128;

  f32x4 acc[4][4];
  #pragma unroll
  for (int i = 0; i < 4; ++i)
    #pragma unroll
    for (int j = 0; j < 4; ++j)
      #pragma unroll
      for (int e = 0; e < 4; ++e) acc[i][j][e] = 0.f;

  const int arow = lane >> 3;                  // 8 rows / 1KB issue (f32)
  const int aglog = (lane & 7) ^ arow;         // swizzled source granule
  const int brow = lane >> 2;                  // 16 rows / 1KB issue (bf16)
  const int bglog = (lane & 3) ^ (brow & 3);

  auto stage = [&](int k0, int buf) {
    #pragma unroll
    for (int s = 0; s < 4; ++s) {
      int e = w * 4 + s;
      int col = k0 + aglog * 4;
      if (col >= XSZ) col = 0;                 // pad lanes: finite garbage * B(0) = 0
      const float* g = x + (size_t)(LEAF0 + tileM + e * 8 + arow) * XSZ + col;
      gld_lds16(g, (char*)As[buf] + e * 1024);
    }
    #pragma unroll
    for (int s = 0; s < 2; ++s) {
      int e = w * 2 + s;
      const unsigned short* g = Wt + (size_t)(tileN + e * 16 + brow) * KX + k0 + bglog * 8;
      gld_lds16(g, (char*)Bs[buf] + e * 1024);
    }
  };

  const int NT = KX / BK;                      // 10
  stage(0, 0);
  for (int it = 0; it < NT; ++it) {
    __syncthreads();                           // tile `it` landed (vmcnt0+lgkm drain)
    if (it + 1 < NT) stage((it + 1) * BK, (it + 1) & 1);
    const int cur = it & 1;
    bf16x8 af[4], bfv[4];
    #pragma unroll
    for (int i = 0; i < 4; ++i) {
      int row = wm * 64 + i * 16 + lr;
      int gx = (2 * ls) ^ (lr & 7);
      f32x4 a0 = *(const f32x4*)((const char*)As[cur] + row * 128 + (gx << 4));
      f32x4 a1 = *(const f32x4*)((const char*)As[cur] + row * 128 + ((gx ^ 1) << 4));
      af[i] = pack8(a0, a1);
    }
    #pragma unroll
    for (int j = 0; j < 4; ++j) {
      int row = wn * 64 + j * 16 + lr;
      bfv[j] = *(const bf16x8*)((const char*)Bs[cur] + row * 64 + ((ls ^ (lr & 3)) << 4));
    }
    #pragma unroll
    for (int i = 0; i < 4; ++i)
      #pragma unroll
      for (int j = 0; j < 4; ++j)
        acc[i][j] = __builtin_amdgcn_mfma_f32_16x16x32_bf16(af[i], bfv[j], acc[i][j], 0, 0, 0);
  }

  const int pc = tileN + wn * 64;
  #pragma unroll
  for (int i = 0; i < 4; ++i) {
    #pragma unroll
    for (int tt = 0; tt < 2; ++tt) {
      int col = (pc >> 1) + tt * 16 + lr;
      #pragma unroll
      for (int rr = 0; rr < 4; ++rr) {
        int row = tileM + wm * 64 + i * 16 + ls * 4 + rr;
        float th = ftanh_(acc[i][2 * tt][rr]     + bW[col]);
        float tc = ftanh_(acc[i][2 * tt + 1][rr] + bW[256 + col]);
        size_t node = (size_t)LEAF0 + row;
        hout[node * HSZ + col] = th;
        cbuf[node * HSZ + col] = tc;
        if constexpr (HB) hb[node * HSZ + col] = f2bf(th);
      }
    }
  }
}

// ---------------------------------------------------------------------------
// One tree level, fused, 2-phase double-buffered.
// ---------------------------------------------------------------------------
template<bool HB>
__global__ __launch_bounds__(256) void k_level_t(
    float* __restrict__ hbuf, unsigned short* __restrict__ hb,
    float* __restrict__ cbuf,
    const unsigned short* __restrict__ Ut, const float* __restrict__ bU,
    int a, int m)
{
  __shared__ __attribute__((aligned(16))) unsigned char  Asb[2][BM * BK * (HB ? 2 : 4)];
  __shared__ __attribute__((aligned(16))) unsigned short Bs[2][BM * BK];
  const int t = threadIdx.x;
  const int lane = t & 63, w = t >> 6;
  const int wm = w >> 1, wn = w & 1;
  const int lr = lane & 15, ls = lane >> 4;

  const int nwg = gridDim.x;
  const int wg = (blockIdx.x & 7) * (nwg >> 3) + (blockIdx.x >> 3);
  const int mblk = wg >> 3, nblk = wg & 7;
  const int tileM = mblk * BM, tileN = nblk * 128;

  f32x4 acc[4][4];
  #pragma unroll
  for (int i = 0; i < 4; ++i)
    #pragma unroll
    for (int j = 0; j < 4; ++j)
      #pragma unroll
      for (int e = 0; e < 4; ++e) acc[i][j][e] = 0.f;

  const unsigned short* AbaseH = hb   + (size_t)(2 * a + 1) * HSZ + (size_t)tileM * KU;
  const float*          AbaseF = hbuf + (size_t)(2 * a + 1) * HSZ + (size_t)tileM * KU;
  const unsigned short* Bbase  = Ut + (size_t)tileN * KU;

  const int arow = lane >> 3;
  const int aglog = (lane & 7) ^ arow;
  const int brow = lane >> 2;
  const int bglog = (lane & 3) ^ (brow & 3);

  auto stage = [&](int k0, int buf) {
    if constexpr (HB) {
      #pragma unroll
      for (int s = 0; s < 2; ++s) {
        int e = w * 2 + s;
        const unsigned short* g = AbaseH + (size_t)(e * 16 + brow) * KU + k0 + bglog * 8;
        gld_lds16(g, (char*)Asb[buf] + e * 1024);
      }
    } else {
      #pragma unroll
      for (int s = 0; s < 4; ++s) {
        int e = w * 4 + s;
        const float* g = AbaseF + (size_t)(e * 8 + arow) * KU + k0 + aglog * 4;
        gld_lds16(g, (char*)Asb[buf] + e * 1024);
      }
    }
    #pragma unroll
    for (int s = 0; s < 2; ++s) {
      int e = w * 2 + s;
      const unsigned short* g = Bbase + (size_t)(e * 16 + brow) * KU + k0 + bglog * 8;
      gld_lds16(g, (char*)Bs[buf] + e * 1024);
    }
  };

  const int NT = KU / BK;                      // 16
  stage(0, 0);
  for (int it = 0; it < NT; ++it) {
    __syncthreads();
    if (it + 1 < NT) stage((it + 1) * BK, (it + 1) & 1);
    const int cur = it & 1;
    bf16x8 af[4], bfv[4];
    #pragma unroll
    for (int i = 0; i < 4; ++i) {
      int row = wm * 64 + i * 16 + lr;
      if constexpr (HB) {
        af[i] = *(const bf16x8*)((const char*)Asb[cur] + row * 64 + ((ls ^ (lr & 3)) << 4));
      } else {
        int gx = (2 * ls) ^ (lr & 7);
        f32x4 a0 = *(const f32x4*)((const char*)Asb[cur] + row * 128 + (gx << 4));
        f32x4 a1 = *(const f32x4*)((const char*)Asb[cur] + row * 128 + ((gx ^ 1) << 4));
        af[i] = pack8(a0, a1);
      }
    }
    #pragma unroll
    for (int j = 0; j < 4; ++j) {
      int row = wn * 64 + j * 16 + lr;
      bfv[j] = *(const bf16x8*)((const char*)Bs[cur] + row * 64 + ((ls ^ (lr & 3)) << 4));
    }
    #pragma unroll
    for (int i = 0; i < 4; ++i)
      #pragma unroll
      for (int j = 0; j < 4; ++j)
        acc[i][j] = __builtin_amdgcn_mfma_f32_16x16x32_bf16(af[i], bfv[j], acc[i][j], 0, 0, 0);
  }

  const int pc = tileN + wn * 64;            // frag j == gate g
  const int col = (pc >> 2) + lr;
  const float bi = bU[col], bo = bU[256 + col], bu = bU[512 + col], bff = bU[768 + col];
  #pragma unroll
  for (int i = 0; i < 4; ++i) {
    #pragma unroll
    for (int rr = 0; rr < 4; ++rr) {
      int noderow = tileM + wm * 64 + i * 16 + ls * 4 + rr;
      if (noderow < m) {
        float iv = fsig  (acc[i][0][rr] + bi);
        float ov = fsig  (acc[i][1][rr] + bo);
        float uv = ftanh_(acc[i][2][rr] + bu);
        float fv = fsig  (acc[i][3][rr] + bff);
        size_t node = (size_t)a + noderow;
        float cl = cbuf[(2 * node + 1) * HSZ + col];
        float cr = cbuf[(2 * node + 2) * HSZ + col];
        float cn = iv * uv + fv * (cl + cr);
        float hn = ov * ftanh_(cn);
        hbuf[node * HSZ + col] = hn;
        cbuf[node * HSZ + col] = cn;
        if constexpr (HB) hb[node * HSZ + col] = f2bf(hn);
      }
    }
  }
}

// ---------------------------------------------------------------------------
extern "C" void kernel_launch(void* const* d_in, const int* in_sizes, int n_in,
                              void* d_out, int out_size, void* d_ws, size_t ws_size,
                              hipStream_t stream) {
  const float* x  = (const float*)d_in[0];
  const float* W  = (const float*)d_in[1];
  const float* bW = (const float*)d_in[2];
  const float* U  = (const float*)d_in[3];
  const float* bU = (const float*)d_in[4];
  // d_in[5] = children (int32) — structurally 2i+1/2i+2 (complete binary tree).
  float* hout = (float*)d_out;
  char*  ws   = (char*)d_ws;

  unsigned short* Ut = (unsigned short*)ws;                       // 1 MiB
  unsigned short* Wt = (unsigned short*)(ws + 1048576);           // 320 KiB
  float* cbuf = (float*)(ws + 1048576 + 327680);                  // 268.4 MB
  size_t base = 1048576 + 327680 + (size_t)N_NODES * HSZ * 4;
  size_t hbsz = (size_t)N_NODES * HSZ * 2;                        // 134.2 MB
  bool use_hb = (ws_size >= base + hbsz);
  unsigned short* hb = (unsigned short*)(ws + base);

  const int preptot = GATES * KU + WCOLS * KX;
  hipLaunchKernelGGL(k_prep, dim3((preptot + 255) / 256), dim3(256), 0, stream, W, U, Wt, Ut);

  if (use_hb) {
    hipLaunchKernelGGL(k_init_t<true>, dim3((N_LEAF / BM) * 4), dim3(256), 0, stream,
                       x, Wt, bW, hout, hb, cbuf);
    for (int d = 16; d >= 0; --d) {
      int m = 1 << d, a = m - 1;
      int mb = (m + BM - 1) / BM;
      hipLaunchKernelGGL(k_level_t<true>, dim3(mb * 8), dim3(256), 0, stream,
                         hout, hb, cbuf, Ut, bU, a, m);
    }
  } else {
    hipLaunchKernelGGL(k_init_t<false>, dim3((N_LEAF / BM) * 4), dim3(256), 0, stream,
                       x, Wt, bW, hout, hb, cbuf);
    for (int d = 16; d >= 0; --d) {
      int m = 1 << d, a = m - 1;
      int mb = (m + BM - 1) / BM;
      hipLaunchKernelGGL(k_level_t<false>, dim3(mb * 8), dim3(256), 0, stream,
                         hout, hb, cbuf, Ut, bU, a, m);
    }
  }
}

// Round 6
// 591.745 us; speedup vs baseline: 1.6637x; 1.1779x over previous
//
#include <hip/hip_runtime.h>
#include <hip/hip_bf16.h>
#include <cstdint>
#include <cstddef>

#define N_NODES 262143
#define LEAF0   131071
#define N_LEAF  131072
#define HSZ     256
#define XSZ     300
#define KX      320        // XSZ padded to multiple of 32
#define KU      512
#define GATES   1024       // 4*H
#define WCOLS   512        // 2*H
#define BM      128
#define BK      32

typedef short bf16x8 __attribute__((ext_vector_type(8)));
typedef float f32x4 __attribute__((ext_vector_type(4)));
typedef _Float16 f16;

__device__ __forceinline__ unsigned short f2bf(float f) {
  union { float f; unsigned u; } v; v.f = f;
  unsigned r = v.u + 0x7FFFu + ((v.u >> 16) & 1u);   // RNE
  return (unsigned short)(r >> 16);
}
__device__ __forceinline__ unsigned cvt_pk(float lo, float hi) {
  unsigned r;
  asm("v_cvt_pk_bf16_f32 %0, %1, %2" : "=v"(r) : "v"(lo), "v"(hi));
  return r;
}
__device__ __forceinline__ bf16x8 pack8(f32x4 a0, f32x4 a1) {
  union { unsigned u[4]; bf16x8 v; } r;
  r.u[0] = cvt_pk(a0[0], a0[1]);
  r.u[1] = cvt_pk(a0[2], a0[3]);
  r.u[2] = cvt_pk(a1[0], a1[1]);
  r.u[3] = cvt_pk(a1[2], a1[3]);
  return r.v;
}
__device__ __forceinline__ void gld_lds16(const void* g, void* l) {
  __builtin_amdgcn_global_load_lds(
      (const __attribute__((address_space(1))) unsigned*)g,
      (__attribute__((address_space(3))) unsigned*)l, 16, 0, 0);
}
__device__ __forceinline__ float frcp(float x) { return __builtin_amdgcn_rcpf(x); }
__device__ __forceinline__ float fsig(float x) { return frcp(1.f + __expf(-x)); }
__device__ __forceinline__ float ftanh_(float x) { return 1.f - 2.f * frcp(1.f + __expf(2.f * x)); }

// ---------------------------------------------------------------------------
// Prep: cast + column-permute + transpose W and U into ws (bf16).
// U perm col p = 64*b + 16*g + j  <-  orig col 256*g + 16*b + j
// W perm col p = 32*b + 16*s + j  <-  orig col 256*s + 16*b + j
// ---------------------------------------------------------------------------
__global__ void k_prep(const float* __restrict__ W, const float* __restrict__ U,
                       unsigned short* __restrict__ Wt, unsigned short* __restrict__ Ut) {
  int tid = blockIdx.x * blockDim.x + threadIdx.x;
  const int totalU = GATES * KU;
  if (tid < totalU) {
    int p = tid >> 9;
    int k = tid & 511;
    int g = (p >> 4) & 3, b = p >> 6, j = p & 15;
    int oc = g * 256 + b * 16 + j;
    Ut[tid] = f2bf(U[(size_t)k * GATES + oc]);
  } else {
    int t2 = tid - totalU;
    if (t2 < WCOLS * KX) {
      int p = t2 / KX;
      int k = t2 - p * KX;
      int s = (p >> 4) & 1, b = p >> 5, j = p & 15;
      int oc = s * 256 + b * 16 + j;
      Wt[t2] = (k < XSZ) ? f2bf(W[(size_t)k * WCOLS + oc]) : (unsigned short)0;
    }
  }
}

// ---------------------------------------------------------------------------
// Leaf init: t = tanh(x @ W + bW); h -> hout(f32)+hb(bf16), c -> cb(f16)
// A = x f32 (8-granule XOR swizzle), B = Wt bf16 (4-granule XOR swizzle).
// ---------------------------------------------------------------------------
__global__ __launch_bounds__(256) void k_init(
    const float* __restrict__ x, const unsigned short* __restrict__ Wt,
    const float* __restrict__ bW, float* __restrict__ hout,
    unsigned short* __restrict__ hb, f16* __restrict__ cb)
{
  __shared__ __attribute__((aligned(16))) float          As[2][BM * BK];   // 2x16 KB
  __shared__ __attribute__((aligned(16))) unsigned short Bs[2][BM * BK];   // 2x 8 KB
  const int t = threadIdx.x;
  const int lane = t & 63, w = t >> 6;
  const int wm = w >> 1, wn = w & 1;
  const int lr = lane & 15, ls = lane >> 4;

  const int nwg = gridDim.x;
  const int wg = (blockIdx.x & 7) * (nwg >> 3) + (blockIdx.x >> 3);
  const int mblk = wg >> 2, nblk = wg & 3;
  const int tileM = mblk * BM, tileN = nblk * 128;

  f32x4 acc[4][4];
  #pragma unroll
  for (int i = 0; i < 4; ++i)
    #pragma unroll
    for (int j = 0; j < 4; ++j)
      #pragma unroll
      for (int e = 0; e < 4; ++e) acc[i][j][e] = 0.f;

  const int arow  = lane >> 3;                       // A: 8 rows / 1KB issue (f32)
  const int aglog = (lane & 7) ^ arow;               // src granule = g ^ (row&7)
  const int brow  = lane >> 2;                       // B: 16 rows / 1KB issue (bf16)
  const int bswz  = ((lane & 3) ^ ((lane >> 3) & 3)) * 8;  // src elems = (g^((row>>1)&3))*8

  auto stage = [&](int k0, int buf) {
    #pragma unroll
    for (int s = 0; s < 4; ++s) {
      int e = w * 4 + s;
      int col = k0 + aglog * 4;
      if (col >= XSZ) col = 0;                 // pad lanes: finite garbage * B(0) = 0
      const float* g = x + (size_t)(LEAF0 + tileM + e * 8 + arow) * XSZ + col;
      gld_lds16(g, (char*)As[buf] + e * 1024);
    }
    #pragma unroll
    for (int s = 0; s < 2; ++s) {
      int e = w * 2 + s;
      const unsigned short* g = Wt + (size_t)(tileN + e * 16 + brow) * KX + k0 + bswz;
      gld_lds16(g, (char*)Bs[buf] + e * 1024);
    }
  };

  const int NT = KX / BK;                      // 10
  stage(0, 0);
  for (int it = 0; it < NT; ++it) {
    __syncthreads();
    if (it + 1 < NT) stage((it + 1) * BK, (it + 1) & 1);
    const int cur = it & 1;
    bf16x8 af[4], bfv[4];
    #pragma unroll
    for (int i = 0; i < 4; ++i) {
      int row = wm * 64 + i * 16 + lr;
      int gx = (2 * ls) ^ (lr & 7);
      f32x4 a0 = *(const f32x4*)((const char*)As[cur] + row * 128 + (gx << 4));
      f32x4 a1 = *(const f32x4*)((const char*)As[cur] + row * 128 + ((gx ^ 1) << 4));
      af[i] = pack8(a0, a1);
    }
    #pragma unroll
    for (int j = 0; j < 4; ++j) {
      int row = wn * 64 + j * 16 + lr;
      bfv[j] = *(const bf16x8*)((const char*)Bs[cur] + row * 64 + ((ls ^ ((lr >> 1) & 3)) << 4));
    }
    #pragma unroll
    for (int i = 0; i < 4; ++i)
      #pragma unroll
      for (int j = 0; j < 4; ++j)
        acc[i][j] = __builtin_amdgcn_mfma_f32_16x16x32_bf16(af[i], bfv[j], acc[i][j], 0, 0, 0);
  }

  const int pc = tileN + wn * 64;
  #pragma unroll
  for (int i = 0; i < 4; ++i) {
    #pragma unroll
    for (int tt = 0; tt < 2; ++tt) {
      int col = (pc >> 1) + tt * 16 + lr;
      #pragma unroll
      for (int rr = 0; rr < 4; ++rr) {
        int row = tileM + wm * 64 + i * 16 + ls * 4 + rr;
        float th = ftanh_(acc[i][2 * tt][rr]     + bW[col]);
        float tc = ftanh_(acc[i][2 * tt + 1][rr] + bW[256 + col]);
        size_t node = (size_t)LEAF0 + row;
        hout[node * HSZ + col] = th;
        hb[node * HSZ + col]   = f2bf(th);
        cb[node * HSZ + col]   = (f16)tc;
      }
    }
  }
}

// ---------------------------------------------------------------------------
// One tree level (d >= 12), fused, all-bf16 staging, 2-phase dbuf.
// ---------------------------------------------------------------------------
__global__ __launch_bounds__(256) void k_level(
    float* __restrict__ hbuf, unsigned short* __restrict__ hb,
    f16* __restrict__ cb,
    const unsigned short* __restrict__ Ut, const float* __restrict__ bU,
    int a, int m)
{
  __shared__ __attribute__((aligned(16))) unsigned short As[2][BM * BK];   // 2x8 KB
  __shared__ __attribute__((aligned(16))) unsigned short Bs[2][BM * BK];   // 2x8 KB
  const int t = threadIdx.x;
  const int lane = t & 63, w = t >> 6;
  const int wm = w >> 1, wn = w & 1;
  const int lr = lane & 15, ls = lane >> 4;

  const int nwg = gridDim.x;
  const int wg = (blockIdx.x & 7) * (nwg >> 3) + (blockIdx.x >> 3);
  const int mblk = wg >> 3, nblk = wg & 7;
  const int tileM = mblk * BM, tileN = nblk * 128;

  f32x4 acc[4][4];
  #pragma unroll
  for (int i = 0; i < 4; ++i)
    #pragma unroll
    for (int j = 0; j < 4; ++j)
      #pragma unroll
      for (int e = 0; e < 4; ++e) acc[i][j][e] = 0.f;

  const unsigned short* Abase = hb + (size_t)(2 * a + 1) * HSZ + (size_t)tileM * KU;
  const unsigned short* Bbase = Ut + (size_t)tileN * KU;

  const int brow = lane >> 2;
  const int bswz = ((lane & 3) ^ ((lane >> 3) & 3)) * 8;

  auto stage = [&](int k0, int buf) {
    #pragma unroll
    for (int s = 0; s < 2; ++s) {
      int e = w * 2 + s;
      const unsigned short* g = Abase + (size_t)(e * 16 + brow) * KU + k0 + bswz;
      gld_lds16(g, (char*)As[buf] + e * 1024);
    }
    #pragma unroll
    for (int s = 0; s < 2; ++s) {
      int e = w * 2 + s;
      const unsigned short* g = Bbase + (size_t)(e * 16 + brow) * KU + k0 + bswz;
      gld_lds16(g, (char*)Bs[buf] + e * 1024);
    }
  };

  const int NT = KU / BK;                      // 16
  stage(0, 0);
  for (int it = 0; it < NT; ++it) {
    __syncthreads();
    if (it + 1 < NT) stage((it + 1) * BK, (it + 1) & 1);
    const int cur = it & 1;
    bf16x8 af[4], bfv[4];
    #pragma unroll
    for (int i = 0; i < 4; ++i) {
      int row = wm * 64 + i * 16 + lr;
      af[i] = *(const bf16x8*)((const char*)As[cur] + row * 64 + ((ls ^ ((lr >> 1) & 3)) << 4));
    }
    #pragma unroll
    for (int j = 0; j < 4; ++j) {
      int row = wn * 64 + j * 16 + lr;
      bfv[j] = *(const bf16x8*)((const char*)Bs[cur] + row * 64 + ((ls ^ ((lr >> 1) & 3)) << 4));
    }
    #pragma unroll
    for (int i = 0; i < 4; ++i)
      #pragma unroll
      for (int j = 0; j < 4; ++j)
        acc[i][j] = __builtin_amdgcn_mfma_f32_16x16x32_bf16(af[i], bfv[j], acc[i][j], 0, 0, 0);
  }

  const int pc = tileN + wn * 64;            // frag j == gate g
  const int col = (pc >> 2) + lr;
  const float bi = bU[col], bo = bU[256 + col], bu = bU[512 + col], bff = bU[768 + col];
  #pragma unroll
  for (int i = 0; i < 4; ++i) {
    #pragma unroll
    for (int rr = 0; rr < 4; ++rr) {
      int noderow = tileM + wm * 64 + i * 16 + ls * 4 + rr;
      if (noderow < m) {
        float iv = fsig  (acc[i][0][rr] + bi);
        float ov = fsig  (acc[i][1][rr] + bo);
        float uv = ftanh_(acc[i][2][rr] + bu);
        float fv = fsig  (acc[i][3][rr] + bff);
        size_t node = (size_t)a + noderow;
        float cl = (float)cb[(2 * node + 1) * HSZ + col];
        float cr = (float)cb[(2 * node + 2) * HSZ + col];
        float cn = iv * uv + fv * (cl + cr);
        float hn = ov * ftanh_(cn);
        hbuf[node * HSZ + col] = hn;
        hb[node * HSZ + col]   = f2bf(hn);
        cb[node * HSZ + col]   = (f16)cn;
      }
    }
  }
}

// ---------------------------------------------------------------------------
// Small levels (d <= 11): no LDS, no barriers. One wave per 16x64 output tile,
// A/B straight from global (L2/L3-resident); compiler free-pipelines the loop.
// grid = max(1,m/64) * 16 blocks of 256 (4 waves; wave w -> rows bm*64+w*16..).
// ---------------------------------------------------------------------------
__global__ __launch_bounds__(256) void k_small(
    float* __restrict__ hbuf, unsigned short* __restrict__ hb,
    f16* __restrict__ cb,
    const unsigned short* __restrict__ Ut, const float* __restrict__ bU,
    int a, int m)
{
  const int t = threadIdx.x;
  const int lane = t & 63, w = t >> 6;
  const int lr = lane & 15, ls = lane >> 4;
  const int rb = (blockIdx.x >> 4) * 64 + w * 16;
  const int nb = (blockIdx.x & 15) * 64;
  if (rb >= m) return;

  const unsigned short* Arow = hb + (size_t)(2 * a + 1) * HSZ + (size_t)(rb + lr) * KU;
  const unsigned short* B0 = Ut + (size_t)(nb + lr) * KU;

  f32x4 acc[4];
  #pragma unroll
  for (int g = 0; g < 4; ++g)
    #pragma unroll
    for (int e = 0; e < 4; ++e) acc[g][e] = 0.f;

  for (int k0 = 0; k0 < KU; k0 += BK) {
    bf16x8 av = *(const bf16x8*)(Arow + k0 + ls * 8);
    #pragma unroll
    for (int g = 0; g < 4; ++g) {
      bf16x8 bv = *(const bf16x8*)(B0 + (size_t)g * 16 * KU + k0 + ls * 8);
      acc[g] = __builtin_amdgcn_mfma_f32_16x16x32_bf16(av, bv, acc[g], 0, 0, 0);
    }
  }

  const int col = (nb >> 2) + lr;
  const float bi = bU[col], bo = bU[256 + col], bu = bU[512 + col], bff = bU[768 + col];
  #pragma unroll
  for (int rr = 0; rr < 4; ++rr) {
    int row = rb + ls * 4 + rr;
    if (row < m) {
      float iv = fsig  (acc[0][rr] + bi);
      float ov = fsig  (acc[1][rr] + bo);
      float uv = ftanh_(acc[2][rr] + bu);
      float fv = fsig  (acc[3][rr] + bff);
      size_t node = (size_t)a + row;
      float cl = (float)cb[(2 * node + 1) * HSZ + col];
      float cr = (float)cb[(2 * node + 2) * HSZ + col];
      float cn = iv * uv + fv * (cl + cr);
      float hn = ov * ftanh_(cn);
      hbuf[node * HSZ + col] = hn;
      hb[node * HSZ + col]   = f2bf(hn);
      cb[node * HSZ + col]   = (f16)cn;
    }
  }
}

// ---------------------------------------------------------------------------
extern "C" void kernel_launch(void* const* d_in, const int* in_sizes, int n_in,
                              void* d_out, int out_size, void* d_ws, size_t ws_size,
                              hipStream_t stream) {
  const float* x  = (const float*)d_in[0];
  const float* W  = (const float*)d_in[1];
  const float* bW = (const float*)d_in[2];
  const float* U  = (const float*)d_in[3];
  const float* bU = (const float*)d_in[4];
  // d_in[5] = children (int32) — structurally 2i+1/2i+2 (complete binary tree).
  float* hout = (float*)d_out;
  char*  ws   = (char*)d_ws;

  // ws layout (269,810,688 B total — identical footprint to prior rounds):
  unsigned short* Ut = (unsigned short*)ws;                         // 1,048,576
  unsigned short* Wt = (unsigned short*)(ws + 1048576);             //   327,680
  f16*            cb = (f16*)(ws + 1048576 + 327680);               // 134,217,216
  unsigned short* hb = (unsigned short*)(ws + 1048576 + 327680
                                         + (size_t)N_NODES * HSZ * 2); // 134,217,216

  const int preptot = GATES * KU + WCOLS * KX;
  hipLaunchKernelGGL(k_prep, dim3((preptot + 255) / 256), dim3(256), 0, stream, W, U, Wt, Ut);

  hipLaunchKernelGGL(k_init, dim3((N_LEAF / BM) * 4), dim3(256), 0, stream,
                     x, Wt, bW, hout, hb, cb);

  for (int d = 16; d >= 0; --d) {
    int m = 1 << d, a = m - 1;
    if (d >= 12) {
      hipLaunchKernelGGL(k_level, dim3((m / BM) * 8), dim3(256), 0, stream,
                         hout, hb, cb, Ut, bU, a, m);
    } else {
      int gm = (m + 63) / 64; if (gm < 1) gm = 1;
      hipLaunchKernelGGL(k_small, dim3(gm * 16), dim3(256), 0, stream,
                         hout, hb, cb, Ut, bU, a, m);
    }
  }
}